// Round 2
// baseline (660.518 us; speedup 1.0000x reference)
//
#include <hip/hip_runtime.h>

#define NP 256      // P
#define NDD 128     // DD
#define NN 1024     // N
#define NE 250000   // E

// ---------------------------------------------------------------------------
// K1: refine rows [target; form(1024); role(1024)] : z = W2 @ prelu(W1 @ x + b1) + b2
// 8 rows per block, 256 threads (thread = output feature), f32 out to ws.
// ---------------------------------------------------------------------------
__global__ __launch_bounds__(256) void refine_kernel(
    const float* __restrict__ tgt, const float* __restrict__ formf, const float* __restrict__ rolef,
    const float* __restrict__ Wr1, const float* __restrict__ br1, const float* __restrict__ ar1,
    const float* __restrict__ Wr2, const float* __restrict__ br2,
    float* __restrict__ zt, float* __restrict__ zf, float* __restrict__ zr)
{
  __shared__ float X[8][NP];
  __shared__ float H[8][NP];
  const int t = threadIdx.x;
  const int base = blockIdx.x * 8;
  #pragma unroll
  for (int r = 0; r < 8; r++){
    int row = base + r;
    if (row < 2*NN + 1){
      const float* xp;
      if (row == 0)        xp = tgt;
      else if (row <= NN)  xp = formf + (size_t)(row-1)*NP;
      else                 xp = rolef + (size_t)(row-NN-1)*NP;
      X[r][t] = xp[t];
    } else {
      X[r][t] = 0.f;
    }
  }
  __syncthreads();
  const float a1 = ar1[0];
  float acc[8];
  #pragma unroll
  for (int r = 0; r < 8; r++) acc[r] = 0.f;
  const float4* w1p = reinterpret_cast<const float4*>(Wr1) + t*(NP/4);
  for (int k4 = 0; k4 < NP/4; k4++){
    float4 w = w1p[k4];
    #pragma unroll
    for (int r = 0; r < 8; r++){
      float4 xv = *reinterpret_cast<const float4*>(&X[r][k4*4]);
      acc[r] = fmaf(w.x, xv.x, acc[r]);
      acc[r] = fmaf(w.y, xv.y, acc[r]);
      acc[r] = fmaf(w.z, xv.z, acc[r]);
      acc[r] = fmaf(w.w, xv.w, acc[r]);
    }
  }
  const float b1 = br1[t];
  #pragma unroll
  for (int r = 0; r < 8; r++){
    float h = acc[r] + b1;
    H[r][t] = h >= 0.f ? h : a1*h;
  }
  __syncthreads();
  #pragma unroll
  for (int r = 0; r < 8; r++) acc[r] = 0.f;
  const float4* w2p = reinterpret_cast<const float4*>(Wr2) + t*(NP/4);
  for (int k4 = 0; k4 < NP/4; k4++){
    float4 w = w2p[k4];
    #pragma unroll
    for (int r = 0; r < 8; r++){
      float4 hv = *reinterpret_cast<const float4*>(&H[r][k4*4]);
      acc[r] = fmaf(w.x, hv.x, acc[r]);
      acc[r] = fmaf(w.y, hv.y, acc[r]);
      acc[r] = fmaf(w.z, hv.z, acc[r]);
      acc[r] = fmaf(w.w, hv.w, acc[r]);
    }
  }
  const float b2 = br2[t];
  #pragma unroll
  for (int r = 0; r < 8; r++){
    int row = base + r;
    if (row < 2*NN + 1){
      float v = acc[r] + b2;
      float* op;
      if (row == 0)        op = zt;
      else if (row <= NN)  op = zf + (size_t)(row-1)*NP;
      else                 op = zr + (size_t)(row-NN-1)*NP;
      op[t] = v;
    }
  }
}

// ---------------------------------------------------------------------------
// K2: Qv = Wq@zt + bq ; qk = (Wk^T @ Qv)/sqrt(DD) ; s0 = (bk . Qv)/sqrt(DD)
// ---------------------------------------------------------------------------
__global__ __launch_bounds__(128) void qk_kernel(
    const float* __restrict__ zt,
    const float* __restrict__ Wq, const float* __restrict__ bq,
    const float* __restrict__ Wk, const float* __restrict__ bk,
    float* __restrict__ qk, float* __restrict__ s0)
{
  __shared__ float Z[NP];
  __shared__ float Q[NDD];
  __shared__ float red[NDD];
  int t = threadIdx.x;
  Z[t] = zt[t]; Z[t+128] = zt[t+128];
  __syncthreads();
  float acc = 0.f;
  const float4* wq = reinterpret_cast<const float4*>(Wq) + t*(NP/4);
  for (int k4 = 0; k4 < NP/4; k4++){
    float4 w = wq[k4];
    float4 zv = *reinterpret_cast<const float4*>(&Z[k4*4]);
    acc = fmaf(w.x, zv.x, fmaf(w.y, zv.y, fmaf(w.z, zv.z, fmaf(w.w, zv.w, acc))));
  }
  float qv = acc + bq[t];
  Q[t] = qv;
  __syncthreads();
  float a2 = 0.f;
  for (int j = 0; j < NDD; j++) a2 = fmaf(Wk[j*NDD + t], Q[j], a2);
  const float rs = 0.08838834764831845f;  // 1/sqrt(128)
  qk[t] = a2 * rs;
  red[t] = bk[t] * qv;
  __syncthreads();
  for (int o = 64; o; o >>= 1){ if (t < o) red[t] += red[t+o]; __syncthreads(); }
  if (t == 0) s0[0] = red[0] * rs;
}

// ---------------------------------------------------------------------------
// Counting sort of edges by segment (segment = searchsorted(neighbors, src))
// ---------------------------------------------------------------------------
__global__ __launch_bounds__(256) void hist_kernel(
    const int* __restrict__ neigh, const int* __restrict__ src,
    int* __restrict__ count)
{
  __shared__ int NB[NN];
  int t = threadIdx.x;
  #pragma unroll
  for (int i = 0; i < NN/256; i++) NB[t + i*256] = neigh[t + i*256];
  __syncthreads();
  int e = blockIdx.x*256 + t;
  if (e >= NE) return;
  int s = src[e];
  int lo = 0, hi = NN;
  while (lo < hi){ int mid = (lo+hi)>>1; if (NB[mid] < s) lo = mid+1; else hi = mid; }
  int pos = lo < NN ? lo : NN-1;
  if (NB[pos] == s) atomicAdd(&count[pos], 1);
}

__global__ __launch_bounds__(1024) void scan_kernel(
    const int* __restrict__ count, int* __restrict__ offsets, int* __restrict__ cursor)
{
  __shared__ int s[NN];
  int l = blockIdx.x;
  int t = threadIdx.x;
  int c = count[l*NN + t];
  s[t] = c; __syncthreads();
  for (int o = 1; o < NN; o <<= 1){
    int v = (t >= o) ? s[t-o] : 0;
    __syncthreads();
    s[t] += v;
    __syncthreads();
  }
  int ex = s[t] - c;
  offsets[l*NN + t] = ex;
  cursor[l*NN + t]  = ex;
}

__global__ __launch_bounds__(256) void scatter_kernel(
    const int* __restrict__ neigh, const int* __restrict__ src,
    const int* __restrict__ dst, const float* __restrict__ yb,
    int* __restrict__ cursor, int* __restrict__ sdst, float* __restrict__ sy)
{
  __shared__ int NB[NN];
  int t = threadIdx.x;
  #pragma unroll
  for (int i = 0; i < NN/256; i++) NB[t + i*256] = neigh[t + i*256];
  __syncthreads();
  int e = blockIdx.x*256 + t;
  if (e >= NE) return;
  int s = src[e];
  int lo = 0, hi = NN;
  while (lo < hi){ int mid = (lo+hi)>>1; if (NB[mid] < s) lo = mid+1; else hi = mid; }
  int pos = lo < NN ? lo : NN-1;
  if (NB[pos] == s){
    int p = atomicAdd(&cursor[pos], 1);
    sdst[p] = dst[e];
    sy[p]   = yb[e];
  }
}

// ---------------------------------------------------------------------------
// K6: per-(layer,segment) online softmax over its edges.
// One wave per edge iteration; lane holds dims (2l, 2l+1) of the drug row.
// Accumulates m, den, c = sum ex*(y-6), g = sum ex*(y-6)*d  in registers.
// ---------------------------------------------------------------------------
__global__ __launch_bounds__(256) void seg_kernel(
    const float* __restrict__ drug,
    const int* __restrict__ sdst, const float* __restrict__ sy,
    const int* __restrict__ offsets, const int* __restrict__ count,
    const float* __restrict__ qk, const float* __restrict__ s0p,
    float* __restrict__ g, float* __restrict__ den, float* __restrict__ cfac)
{
  int b = blockIdx.x;                 // l*1024 + n
  int lane = threadIdx.x & 63, w = threadIdx.x >> 6;
  int off = offsets[b], cnt = count[b];
  int l = b >> 10;
  const int*   dsts = sdst + (size_t)l*NE;
  const float* ys   = sy   + (size_t)l*NE;
  float q0 = qk[2*lane], q1 = qk[2*lane + 1];
  float s0 = s0p[0];
  float m = -INFINITY, dn = 0.f, cc = 0.f, g0 = 0.f, g1 = 0.f;
  for (int i = w; i < cnt; i += 4){
    int e = off + i;
    int dst = dsts[e];
    float y = ys[e];
    float2 u = *(reinterpret_cast<const float2*>(drug + (size_t)dst*NDD) + lane);
    float d0 = u.x, d1 = u.y;
    float p = fmaf(d0, q0, d1*q1);
    #pragma unroll
    for (int o = 32; o; o >>= 1) p += __shfl_xor(p, o, 64);
    float sv = p + s0;
    float mn = fmaxf(m, sv);
    float sc = __expf(m - mn);          // 0 on first iteration (m = -inf)
    float ex = __expf(sv - mn);
    float wv = ex * (y - 6.0f);
    dn = fmaf(dn, sc, ex);
    cc = fmaf(cc, sc, wv);
    g0 = fmaf(g0, sc, wv*d0);
    g1 = fmaf(g1, sc, wv*d1);
    m = mn;
  }
  __shared__ float sM[4], sD[4], sC[4];
  __shared__ float sG[4][NDD];
  if (lane == 0){ sM[w] = m; sD[w] = dn; sC[w] = cc; }
  sG[w][2*lane]     = g0;
  sG[w][2*lane + 1] = g1;
  __syncthreads();
  if (threadIdx.x < NDD){
    int t = threadIdx.x;
    float M = fmaxf(fmaxf(sM[0], sM[1]), fmaxf(sM[2], sM[3]));
    float gs = 0.f, ds = 0.f, cs = 0.f;
    if (M > -INFINITY){
      #pragma unroll
      for (int ww = 0; ww < 4; ww++){
        float sc = __expf(sM[ww] - M);
        gs = fmaf(sG[ww][t], sc, gs);
        ds = fmaf(sD[ww], sc, ds);
        cs = fmaf(sC[ww], sc, cs);
      }
    }
    g[(size_t)b*NDD + t] = gs;
    if (t == 0){ den[b] = ds; cfac[b] = cs; }
  }
}

// ---------------------------------------------------------------------------
// K7: msgs[row] = (Wv @ g[row] + bv*c[row]) / den[row]  (0 if den<=0)
// Writes f32 to d_out (+NP offset) and f32 copy to ws. 8 rows/block, 128 threads.
// ---------------------------------------------------------------------------
__global__ __launch_bounds__(128) void msgs_kernel(
    const float* __restrict__ g, const float* __restrict__ den, const float* __restrict__ cfac,
    const float* __restrict__ Wv, const float* __restrict__ bv,
    float* __restrict__ msgsf, float* __restrict__ outm)
{
  __shared__ float G[8][NDD];
  int t = threadIdx.x;
  int base = blockIdx.x*8;
  #pragma unroll
  for (int r = 0; r < 8; r++) G[r][t] = g[(size_t)(base+r)*NDD + t];
  __syncthreads();
  float acc[8];
  #pragma unroll
  for (int r = 0; r < 8; r++) acc[r] = 0.f;
  const float4* wv4 = reinterpret_cast<const float4*>(Wv) + t*(NDD/4);
  for (int k4 = 0; k4 < NDD/4; k4++){
    float4 w = wv4[k4];
    #pragma unroll
    for (int r = 0; r < 8; r++){
      float4 gv = *reinterpret_cast<const float4*>(&G[r][k4*4]);
      acc[r] = fmaf(w.x, gv.x, acc[r]);
      acc[r] = fmaf(w.y, gv.y, acc[r]);
      acc[r] = fmaf(w.z, gv.z, acc[r]);
      acc[r] = fmaf(w.w, gv.w, acc[r]);
    }
  }
  float bvj = bv[t];
  #pragma unroll
  for (int r = 0; r < 8; r++){
    int row = base + r;
    float dn = den[row];
    float v = 0.f;
    if (dn > 0.f) v = (acc[r] + bvj*cfac[row]) / fmaxf(dn, 1e-30f);
    msgsf[(size_t)row*NDD + t] = v;
    outm [(size_t)row*NDD + t] = v;
  }
}

// ---------------------------------------------------------------------------
// K8: attention logits: a_i = Wa3 @ lrelu(Wa2 @ lrelu(Wa1 @ [zt, zn, le] + ba1) + ba2) + ba3
// 8 nodes/block, 128 threads.
// ---------------------------------------------------------------------------
__global__ __launch_bounds__(128) void attn_kernel(
    const float* __restrict__ zt, const float* __restrict__ zf, const float* __restrict__ zr,
    const float* __restrict__ lemb,
    const float* __restrict__ Wa1, const float* __restrict__ ba1,
    const float* __restrict__ Wa2, const float* __restrict__ ba2,
    const float* __restrict__ Wa3, const float* __restrict__ ba3,
    float* __restrict__ attn)
{
  __shared__ float X[8][528];
  __shared__ float H1[8][NDD];
  int t = threadIdx.x;
  int base = blockIdx.x*8;
  for (int r = 0; r < 8; r++){
    int i = base + r;
    int layer = i >> 10, nn = i & (NN-1);
    const float* zn = (layer == 0) ? (zf + (size_t)nn*NP) : (zr + (size_t)nn*NP);
    for (int idx = t; idx < 528; idx += 128){
      float v;
      if (idx < NP)        v = zt[idx];
      else if (idx < 2*NP) v = zn[idx - NP];
      else                 v = lemb[layer*16 + (idx - 2*NP)];
      X[r][idx] = v;
    }
  }
  __syncthreads();
  float acc[8];
  #pragma unroll
  for (int r = 0; r < 8; r++) acc[r] = 0.f;
  const float4* w1 = reinterpret_cast<const float4*>(Wa1) + t*(528/4);
  for (int k4 = 0; k4 < 132; k4++){
    float4 w = w1[k4];
    #pragma unroll
    for (int r = 0; r < 8; r++){
      float4 xv = *reinterpret_cast<const float4*>(&X[r][k4*4]);
      acc[r] = fmaf(w.x, xv.x, acc[r]);
      acc[r] = fmaf(w.y, xv.y, acc[r]);
      acc[r] = fmaf(w.z, xv.z, acc[r]);
      acc[r] = fmaf(w.w, xv.w, acc[r]);
    }
  }
  float b1 = ba1[t];
  #pragma unroll
  for (int r = 0; r < 8; r++){
    float h = acc[r] + b1;
    H1[r][t] = h >= 0.f ? h : 0.2f*h;
  }
  __syncthreads();
  if (t < 64){
    float acc2[8];
    #pragma unroll
    for (int r = 0; r < 8; r++) acc2[r] = 0.f;
    const float4* w2 = reinterpret_cast<const float4*>(Wa2) + t*(NDD/4);
    for (int k4 = 0; k4 < NDD/4; k4++){
      float4 w = w2[k4];
      #pragma unroll
      for (int r = 0; r < 8; r++){
        float4 hv = *reinterpret_cast<const float4*>(&H1[r][k4*4]);
        acc2[r] = fmaf(w.x, hv.x, acc2[r]);
        acc2[r] = fmaf(w.y, hv.y, acc2[r]);
        acc2[r] = fmaf(w.z, hv.z, acc2[r]);
        acc2[r] = fmaf(w.w, hv.w, acc2[r]);
      }
    }
    float b2 = ba2[t];
    float w3 = Wa3[t];
    float b3 = ba3[0];
    #pragma unroll
    for (int r = 0; r < 8; r++){
      float h = acc2[r] + b2;
      h = h >= 0.f ? h : 0.2f*h;
      float p = w3 * h;
      #pragma unroll
      for (int o = 32; o; o >>= 1) p += __shfl_xor(p, o, 64);
      if (t == 0) attn[base + r] = p + b3;
    }
  }
}

// ---------------------------------------------------------------------------
// K9: softmax over 2048 logits; v_prior = sum_i w_i * msgs_i. One 1024-thread block.
// ---------------------------------------------------------------------------
__global__ __launch_bounds__(1024) void vprior_kernel(
    const float* __restrict__ attn, const float* __restrict__ msgsf, float* __restrict__ vp)
{
  __shared__ float A[2*NN];
  __shared__ float red[1024];
  __shared__ float Pp[8][NDD];
  int t = threadIdx.x;
  A[t] = attn[t]; A[t+1024] = attn[t+1024];
  __syncthreads();
  float mx = fmaxf(A[t], A[t+1024]);
  red[t] = mx; __syncthreads();
  for (int o = 512; o; o >>= 1){ if (t < o) red[t] = fmaxf(red[t], red[t+o]); __syncthreads(); }
  float M = red[0]; __syncthreads();
  float sm = __expf(A[t] - M) + __expf(A[t+1024] - M);
  red[t] = sm; __syncthreads();
  for (int o = 512; o; o >>= 1){ if (t < o) red[t] += red[t+o]; __syncthreads(); }
  float inv = 1.f / red[0]; __syncthreads();
  A[t]      = __expf(A[t]      - M) * inv;
  A[t+1024] = __expf(A[t+1024] - M) * inv;
  __syncthreads();
  int j = t & 127, grp = t >> 7;          // 8 groups x 128 dims
  float acc = 0.f;
  int i0 = grp * 256;
  for (int i = i0; i < i0 + 256; i++) acc = fmaf(A[i], msgsf[(size_t)i*NDD + j], acc);
  Pp[grp][j] = acc;
  __syncthreads();
  if (t < NDD){
    float v = 0.f;
    #pragma unroll
    for (int gg = 0; gg < 8; gg++) v += Pp[gg][t];
    vp[t] = v;
  }
}

// ---------------------------------------------------------------------------
// K10: integ = Wi2 @ prelu(Wi1 @ v_prior + bi1) + bi2 ; x = zt + integ ; layernorm
// ---------------------------------------------------------------------------
__global__ __launch_bounds__(256) void final_kernel(
    const float* __restrict__ vprior, const float* __restrict__ zt,
    const float* __restrict__ Wi1, const float* __restrict__ bi1, const float* __restrict__ ai,
    const float* __restrict__ Wi2, const float* __restrict__ bi2,
    const float* __restrict__ ln_g, const float* __restrict__ ln_b,
    float* __restrict__ zout)
{
  __shared__ float V[NDD];
  __shared__ float T1[NP];
  __shared__ float red[NP];
  int t = threadIdx.x;
  if (t < NDD) V[t] = vprior[t];
  __syncthreads();
  float acc = 0.f;
  const float4* w1 = reinterpret_cast<const float4*>(Wi1) + t*(NDD/4);
  for (int k4 = 0; k4 < NDD/4; k4++){
    float4 w = w1[k4];
    float4 vv = *reinterpret_cast<const float4*>(&V[k4*4]);
    acc = fmaf(w.x, vv.x, fmaf(w.y, vv.y, fmaf(w.z, vv.z, fmaf(w.w, vv.w, acc))));
  }
  float h = acc + bi1[t];
  float a = ai[0];
  T1[t] = h >= 0.f ? h : a*h;
  __syncthreads();
  float acc2 = 0.f;
  const float4* w2 = reinterpret_cast<const float4*>(Wi2) + t*(NP/4);
  for (int k4 = 0; k4 < NP/4; k4++){
    float4 w = w2[k4];
    float4 hv = *reinterpret_cast<const float4*>(&T1[k4*4]);
    acc2 = fmaf(w.x, hv.x, fmaf(w.y, hv.y, fmaf(w.z, hv.z, fmaf(w.w, hv.w, acc2))));
  }
  float x = zt[t] + acc2 + bi2[t];
  red[t] = x; __syncthreads();
  for (int o = 128; o; o >>= 1){ if (t < o) red[t] += red[t+o]; __syncthreads(); }
  float mu = red[0] * (1.f/256.f); __syncthreads();
  float d = x - mu;
  red[t] = d*d; __syncthreads();
  for (int o = 128; o; o >>= 1){ if (t < o) red[t] += red[t+o]; __syncthreads(); }
  float var = red[0] * (1.f/256.f);
  float zz = d * rsqrtf(var + 1e-5f) * ln_g[t] + ln_b[t];
  zout[t] = zz;
}

// ---------------------------------------------------------------------------
extern "C" void kernel_launch(void* const* d_in, const int* in_sizes, int n_in,
                              void* d_out, int out_size, void* d_ws, size_t ws_size,
                              hipStream_t stream)
{
  const float* tgt    = (const float*)d_in[0];
  const float* formf  = (const float*)d_in[1];
  const float* rolef  = (const float*)d_in[2];
  const int* fneigh   = (const int*)d_in[3];
  const int* fsrc     = (const int*)d_in[4];
  const int* fdst     = (const int*)d_in[5];
  const float* fy     = (const float*)d_in[6];
  const int* rneigh   = (const int*)d_in[7];
  const int* rsrc     = (const int*)d_in[8];
  const int* rdst     = (const int*)d_in[9];
  const float* ry     = (const float*)d_in[10];
  const float* drug   = (const float*)d_in[11];
  const float* Wr1 = (const float*)d_in[12];
  const float* br1 = (const float*)d_in[13];
  const float* ar1 = (const float*)d_in[14];
  const float* Wr2 = (const float*)d_in[15];
  const float* br2 = (const float*)d_in[16];
  const float* Wq  = (const float*)d_in[17];
  const float* bq  = (const float*)d_in[18];
  const float* Wk  = (const float*)d_in[19];
  const float* bk  = (const float*)d_in[20];
  const float* Wv  = (const float*)d_in[21];
  const float* bv  = (const float*)d_in[22];
  const float* lemb= (const float*)d_in[23];
  const float* Wa1 = (const float*)d_in[24];
  const float* ba1 = (const float*)d_in[25];
  const float* Wa2 = (const float*)d_in[26];
  const float* ba2 = (const float*)d_in[27];
  const float* Wa3 = (const float*)d_in[28];
  const float* ba3 = (const float*)d_in[29];
  const float* Wi1 = (const float*)d_in[30];
  const float* bi1 = (const float*)d_in[31];
  const float* ai  = (const float*)d_in[32];
  const float* Wi2 = (const float*)d_in[33];
  const float* bi2 = (const float*)d_in[34];
  const float* lng = (const float*)d_in[35];
  const float* lnb = (const float*)d_in[36];
  (void)in_sizes; (void)n_in; (void)out_size; (void)ws_size;

  float* ws = (float*)d_ws;
  // ws layout (float offsets); total 2,061,632 floats (~8.25 MB)
  float* zt_     = ws + 0;
  float* zf_     = ws + 256;
  float* zr_     = ws + 262400;
  float* qk_     = ws + 524544;
  float* s0_     = ws + 524672;
  float* attn_   = ws + 524800;
  float* vprior_ = ws + 526848;
  float* den_    = ws + 527104;
  float* cfac_   = ws + 529152;
  float* g_      = ws + 531200;
  float* msgsf_  = ws + 793344;
  int*   count_  = (int*)(ws + 1055488);
  int*   offs_   = (int*)(ws + 1057536);
  int*   cursor_ = (int*)(ws + 1059584);
  int*   sdst_   = (int*)(ws + 1061632);
  float* sy_     = ws + 1561632;

  hipMemsetAsync(count_, 0, 2*NN*sizeof(int), stream);

  refine_kernel<<<257, 256, 0, stream>>>(tgt, formf, rolef, Wr1, br1, ar1, Wr2, br2,
                                         zt_, zf_, zr_);
  qk_kernel<<<1, 128, 0, stream>>>(zt_, Wq, bq, Wk, bk, qk_, s0_);

  const int EB = (NE + 255)/256;
  hist_kernel<<<EB, 256, 0, stream>>>(fneigh, fsrc, count_);
  hist_kernel<<<EB, 256, 0, stream>>>(rneigh, rsrc, count_ + NN);
  scan_kernel<<<2, 1024, 0, stream>>>(count_, offs_, cursor_);
  scatter_kernel<<<EB, 256, 0, stream>>>(fneigh, fsrc, fdst, fy, cursor_,      sdst_,      sy_);
  scatter_kernel<<<EB, 256, 0, stream>>>(rneigh, rsrc, rdst, ry, cursor_ + NN, sdst_ + NE, sy_ + NE);

  seg_kernel<<<2*NN, 256, 0, stream>>>(drug, sdst_, sy_, offs_, count_, qk_, s0_,
                                       g_, den_, cfac_);

  msgs_kernel<<<2*NN/8, 128, 0, stream>>>(g_, den_, cfac_, Wv, bv,
                                          msgsf_, (float*)d_out + NP);
  attn_kernel<<<2*NN/8, 128, 0, stream>>>(zt_, zf_, zr_, lemb,
                                          Wa1, ba1, Wa2, ba2, Wa3, ba3, attn_);
  vprior_kernel<<<1, 1024, 0, stream>>>(attn_, msgsf_, vprior_);
  final_kernel<<<1, 256, 0, stream>>>(vprior_, zt_, Wi1, bi1, ai, Wi2, bi2,
                                      lng, lnb, (float*)d_out);
}

// Round 3
// 554.690 us; speedup vs baseline: 1.1908x; 1.1908x over previous
//
#include <hip/hip_runtime.h>

#define NP 256      // P
#define NDD 128     // DD
#define NN 1024     // N
#define NE 250000   // E
#define EB 977      // ceil(NE/256)

// ---------------------------------------------------------------------------
// K1: refine rows [target; form(1024); role(1024)] : z = W2 @ prelu(W1 @ x + b1) + b2
// 4 rows per block, 256 threads (thread = output feature), f32 out to ws.
// ---------------------------------------------------------------------------
__global__ __launch_bounds__(256) void refine_kernel(
    const float* __restrict__ tgt, const float* __restrict__ formf, const float* __restrict__ rolef,
    const float* __restrict__ Wr1, const float* __restrict__ br1, const float* __restrict__ ar1,
    const float* __restrict__ Wr2, const float* __restrict__ br2,
    float* __restrict__ zt, float* __restrict__ zf, float* __restrict__ zr)
{
  __shared__ float X[4][NP];
  __shared__ float H[4][NP];
  const int t = threadIdx.x;
  const int base = blockIdx.x * 4;
  #pragma unroll
  for (int r = 0; r < 4; r++){
    int row = base + r;
    if (row < 2*NN + 1){
      const float* xp;
      if (row == 0)        xp = tgt;
      else if (row <= NN)  xp = formf + (size_t)(row-1)*NP;
      else                 xp = rolef + (size_t)(row-NN-1)*NP;
      X[r][t] = xp[t];
    } else {
      X[r][t] = 0.f;
    }
  }
  __syncthreads();
  const float a1 = ar1[0];
  float acc[4];
  #pragma unroll
  for (int r = 0; r < 4; r++) acc[r] = 0.f;
  const float4* w1p = reinterpret_cast<const float4*>(Wr1) + t*(NP/4);
  for (int k4 = 0; k4 < NP/4; k4++){
    float4 w = w1p[k4];
    #pragma unroll
    for (int r = 0; r < 4; r++){
      float4 xv = *reinterpret_cast<const float4*>(&X[r][k4*4]);
      acc[r] = fmaf(w.x, xv.x, acc[r]);
      acc[r] = fmaf(w.y, xv.y, acc[r]);
      acc[r] = fmaf(w.z, xv.z, acc[r]);
      acc[r] = fmaf(w.w, xv.w, acc[r]);
    }
  }
  const float b1 = br1[t];
  #pragma unroll
  for (int r = 0; r < 4; r++){
    float h = acc[r] + b1;
    H[r][t] = h >= 0.f ? h : a1*h;
  }
  __syncthreads();
  #pragma unroll
  for (int r = 0; r < 4; r++) acc[r] = 0.f;
  const float4* w2p = reinterpret_cast<const float4*>(Wr2) + t*(NP/4);
  for (int k4 = 0; k4 < NP/4; k4++){
    float4 w = w2p[k4];
    #pragma unroll
    for (int r = 0; r < 4; r++){
      float4 hv = *reinterpret_cast<const float4*>(&H[r][k4*4]);
      acc[r] = fmaf(w.x, hv.x, acc[r]);
      acc[r] = fmaf(w.y, hv.y, acc[r]);
      acc[r] = fmaf(w.z, hv.z, acc[r]);
      acc[r] = fmaf(w.w, hv.w, acc[r]);
    }
  }
  const float b2 = br2[t];
  #pragma unroll
  for (int r = 0; r < 4; r++){
    int row = base + r;
    if (row < 2*NN + 1){
      float v = acc[r] + b2;
      float* op;
      if (row == 0)        op = zt;
      else if (row <= NN)  op = zf + (size_t)(row-1)*NP;
      else                 op = zr + (size_t)(row-NN-1)*NP;
      op[t] = v;
    }
  }
}

// ---------------------------------------------------------------------------
// K2: Qv = Wq@zt + bq ; qk = (Wk^T @ Qv)/sqrt(DD) ; s0 = (bk . Qv)/sqrt(DD)
// ---------------------------------------------------------------------------
__global__ __launch_bounds__(128) void qk_kernel(
    const float* __restrict__ zt,
    const float* __restrict__ Wq, const float* __restrict__ bq,
    const float* __restrict__ Wk, const float* __restrict__ bk,
    float* __restrict__ qk, float* __restrict__ s0)
{
  __shared__ float Z[NP];
  __shared__ float Q[NDD];
  __shared__ float red[NDD];
  int t = threadIdx.x;
  Z[t] = zt[t]; Z[t+128] = zt[t+128];
  __syncthreads();
  float acc = 0.f;
  const float4* wq = reinterpret_cast<const float4*>(Wq) + t*(NP/4);
  for (int k4 = 0; k4 < NP/4; k4++){
    float4 w = wq[k4];
    float4 zv = *reinterpret_cast<const float4*>(&Z[k4*4]);
    acc = fmaf(w.x, zv.x, fmaf(w.y, zv.y, fmaf(w.z, zv.z, fmaf(w.w, zv.w, acc))));
  }
  float qv = acc + bq[t];
  Q[t] = qv;
  __syncthreads();
  float a2 = 0.f;
  for (int j = 0; j < NDD; j++) a2 = fmaf(Wk[j*NDD + t], Q[j], a2);
  const float rs = 0.08838834764831845f;  // 1/sqrt(128)
  qk[t] = a2 * rs;
  red[t] = bk[t] * qv;
  __syncthreads();
  for (int o = 64; o; o >>= 1){ if (t < o) red[t] += red[t+o]; __syncthreads(); }
  if (t == 0) s0[0] = red[0] * rs;
}

// ---------------------------------------------------------------------------
// Segment id: fast path (sorted int neighbors with neigh[s]==s => pos=s),
// fallback to binary search.
// ---------------------------------------------------------------------------
__device__ __forceinline__ int seg_of(const int* NB, int s){
  if ((unsigned)s < NN && NB[s] == s) return s;
  int lo = 0, hi = NN;
  while (lo < hi){ int mid = (lo+hi)>>1; if (NB[mid] < s) lo = mid+1; else hi = mid; }
  return lo < NN ? lo : NN-1;
}

// ---------------------------------------------------------------------------
// K3: histogram of edges by segment (both layers in one launch)
// ---------------------------------------------------------------------------
__global__ __launch_bounds__(256) void hist_kernel(
    const int* __restrict__ neighF, const int* __restrict__ srcF,
    const int* __restrict__ neighR, const int* __restrict__ srcR,
    int* __restrict__ count)
{
  __shared__ int NB[NN];
  int bi = blockIdx.x;
  int role = bi >= EB ? 1 : 0;
  const int* neigh = role ? neighR : neighF;
  const int* src   = role ? srcR   : srcF;
  int* cnt = count + role*NN;
  int t = threadIdx.x;
  #pragma unroll
  for (int i = 0; i < NN/256; i++) NB[t + i*256] = neigh[t + i*256];
  __syncthreads();
  int e = (bi - role*EB)*256 + t;
  if (e >= NE) return;
  int s = src[e];
  int pos = seg_of(NB, s);
  if (NB[pos] == s) atomicAdd(&cnt[pos], 1);
}

__global__ __launch_bounds__(1024) void scan_kernel(
    const int* __restrict__ count, int* __restrict__ offsets, int* __restrict__ cursor)
{
  __shared__ int s[NN];
  int l = blockIdx.x;
  int t = threadIdx.x;
  int c = count[l*NN + t];
  s[t] = c; __syncthreads();
  for (int o = 1; o < NN; o <<= 1){
    int v = (t >= o) ? s[t-o] : 0;
    __syncthreads();
    s[t] += v;
    __syncthreads();
  }
  int ex = s[t] - c;
  offsets[l*NN + t] = ex;
  cursor[l*NN + t]  = ex;
}

// ---------------------------------------------------------------------------
// K4: scatter edges into segment-sorted order, packing (dst, y) as int2.
// Both layers in one launch.
// ---------------------------------------------------------------------------
__global__ __launch_bounds__(256) void scatter_kernel(
    const int* __restrict__ neighF, const int* __restrict__ srcF,
    const int* __restrict__ dstF, const float* __restrict__ yF,
    const int* __restrict__ neighR, const int* __restrict__ srcR,
    const int* __restrict__ dstR, const float* __restrict__ yR,
    int* __restrict__ cursor, int2* __restrict__ edges)
{
  __shared__ int NB[NN];
  int bi = blockIdx.x;
  int role = bi >= EB ? 1 : 0;
  const int* neigh = role ? neighR : neighF;
  const int* src   = role ? srcR   : srcF;
  const int* dst   = role ? dstR   : dstF;
  const float* yb  = role ? yR     : yF;
  int* cur  = cursor + role*NN;
  int2* ed  = edges  + (size_t)role*NE;
  int t = threadIdx.x;
  #pragma unroll
  for (int i = 0; i < NN/256; i++) NB[t + i*256] = neigh[t + i*256];
  __syncthreads();
  int e = (bi - role*EB)*256 + t;
  if (e >= NE) return;
  int s = src[e];
  int pos = seg_of(NB, s);
  if (NB[pos] == s){
    int p = atomicAdd(&cur[pos], 1);
    ed[p] = make_int2(dst[e], __float_as_int(yb[e]));
  }
}

// ---------------------------------------------------------------------------
// K6: per-(layer,segment) softmax-weighted accumulation.
// 4 waves/block; each 32-lane half-wave handles one edge with float4 lanes
// (32 lanes x 4 dims = 128). 4 pairs (8 edges) batched per iteration for MLP.
// No max-subtraction: logits are O(1e-2), exp safe; num/den invariant.
// ---------------------------------------------------------------------------
__global__ __launch_bounds__(256) void seg_kernel(
    const float* __restrict__ drug,
    const int2* __restrict__ edges,
    const int* __restrict__ offsets, const int* __restrict__ count,
    const float* __restrict__ qk, const float* __restrict__ s0p,
    float* __restrict__ g, float* __restrict__ den, float* __restrict__ cfac)
{
  int b = blockIdx.x;                 // l*1024 + n
  int tid = threadIdx.x;
  int w = tid >> 6, lane = tid & 63, l32 = lane & 31, half = lane >> 5;
  int off = offsets[b], cnt = count[b];
  int l = b >> 10;
  const int2* eb = edges + (size_t)l*NE;
  float4 q = reinterpret_cast<const float4*>(qk)[l32];
  float s0 = s0p[0];
  int chunk = (cnt + 3) >> 2;
  int start = w*chunk;
  int end = min(start + chunk, cnt);
  float dn = 0.f, cc = 0.f;
  float4 ga = make_float4(0.f,0.f,0.f,0.f);
  for (int i = start; i < end; i += 8){
    int dstp[4]; float yp[4]; bool vp[4];
    #pragma unroll
    for (int p2 = 0; p2 < 4; p2++){
      int idx = i + 2*p2 + half;
      bool v = idx < end;
      int2 e = eb[off + (v ? idx : start)];
      dstp[p2] = e.x; yp[p2] = __int_as_float(e.y); vp[p2] = v;
    }
    float4 dv[4];
    #pragma unroll
    for (int p2 = 0; p2 < 4; p2++){
      dv[p2] = reinterpret_cast<const float4*>(drug + (size_t)dstp[p2]*NDD)[l32];
    }
    #pragma unroll
    for (int p2 = 0; p2 < 4; p2++){
      float4 d = dv[p2];
      float s = fmaf(d.x, q.x, fmaf(d.y, q.y, fmaf(d.z, q.z, d.w*q.w)));
      s += __shfl_xor(s, 16, 64);
      s += __shfl_xor(s,  8, 64);
      s += __shfl_xor(s,  4, 64);
      s += __shfl_xor(s,  2, 64);
      s += __shfl_xor(s,  1, 64);
      float ex = vp[p2] ? __expf(s + s0) : 0.f;
      float wv = ex * (yp[p2] - 6.0f);
      dn += ex; cc += wv;
      ga.x = fmaf(wv, d.x, ga.x);
      ga.y = fmaf(wv, d.y, ga.y);
      ga.z = fmaf(wv, d.z, ga.z);
      ga.w = fmaf(wv, d.w, ga.w);
    }
  }
  __shared__ float4 sG[8][32];
  __shared__ float sD[8], sC[8];
  int slot = w*2 + half;
  sG[slot][l32] = ga;
  if (l32 == 0){ sD[slot] = dn; sC[slot] = cc; }
  __syncthreads();
  if (tid < NDD){
    int a = tid >> 2, c = tid & 3;
    float v = 0.f;
    #pragma unroll
    for (int k = 0; k < 8; k++)
      v += reinterpret_cast<const float*>(&sG[k][a])[c];
    g[(size_t)b*NDD + tid] = v;
    if (tid == 0){
      float ds = 0.f, cs = 0.f;
      #pragma unroll
      for (int k = 0; k < 8; k++){ ds += sD[k]; cs += sC[k]; }
      den[b] = ds; cfac[b] = cs;
    }
  }
}

// ---------------------------------------------------------------------------
// K7: msgs[row] = (Wv @ g[row] + bv*c[row]) / den[row]  (0 if den<=0)
// ---------------------------------------------------------------------------
__global__ __launch_bounds__(128) void msgs_kernel(
    const float* __restrict__ g, const float* __restrict__ den, const float* __restrict__ cfac,
    const float* __restrict__ Wv, const float* __restrict__ bv,
    float* __restrict__ msgsf, float* __restrict__ outm)
{
  __shared__ float G[8][NDD];
  int t = threadIdx.x;
  int base = blockIdx.x*8;
  #pragma unroll
  for (int r = 0; r < 8; r++) G[r][t] = g[(size_t)(base+r)*NDD + t];
  __syncthreads();
  float acc[8];
  #pragma unroll
  for (int r = 0; r < 8; r++) acc[r] = 0.f;
  const float4* wv4 = reinterpret_cast<const float4*>(Wv) + t*(NDD/4);
  for (int k4 = 0; k4 < NDD/4; k4++){
    float4 w = wv4[k4];
    #pragma unroll
    for (int r = 0; r < 8; r++){
      float4 gv = *reinterpret_cast<const float4*>(&G[r][k4*4]);
      acc[r] = fmaf(w.x, gv.x, acc[r]);
      acc[r] = fmaf(w.y, gv.y, acc[r]);
      acc[r] = fmaf(w.z, gv.z, acc[r]);
      acc[r] = fmaf(w.w, gv.w, acc[r]);
    }
  }
  float bvj = bv[t];
  #pragma unroll
  for (int r = 0; r < 8; r++){
    int row = base + r;
    float dn = den[row];
    float v = 0.f;
    if (dn > 0.f) v = (acc[r] + bvj*cfac[row]) / fmaxf(dn, 1e-30f);
    msgsf[(size_t)row*NDD + t] = v;
    outm [(size_t)row*NDD + t] = v;
  }
}

// ---------------------------------------------------------------------------
// K8: attention logits. 8 rows/block, 256 threads (2 groups x 128).
// ---------------------------------------------------------------------------
__global__ __launch_bounds__(256) void attn_kernel(
    const float* __restrict__ zt, const float* __restrict__ zf, const float* __restrict__ zr,
    const float* __restrict__ lemb,
    const float* __restrict__ Wa1, const float* __restrict__ ba1,
    const float* __restrict__ Wa2, const float* __restrict__ ba2,
    const float* __restrict__ Wa3, const float* __restrict__ ba3,
    float* __restrict__ attn)
{
  __shared__ float X[8][528];
  __shared__ float H1[8][NDD];
  int t = threadIdx.x;
  int tt = t & 127, grp = t >> 7;
  int base = blockIdx.x*8;
  for (int r = 0; r < 8; r++){
    int i = base + r;
    int layer = i >> 10, nn = i & (NN-1);
    const float* zn = (layer == 0) ? (zf + (size_t)nn*NP) : (zr + (size_t)nn*NP);
    for (int idx = t; idx < 528; idx += 256){
      float v;
      if (idx < NP)        v = zt[idx];
      else if (idx < 2*NP) v = zn[idx - NP];
      else                 v = lemb[layer*16 + (idx - 2*NP)];
      X[r][idx] = v;
    }
  }
  __syncthreads();
  // stage 1: group g computes H1 for rows grp*4 .. grp*4+3, output feature tt
  float acc[4];
  #pragma unroll
  for (int r = 0; r < 4; r++) acc[r] = 0.f;
  const float4* w1 = reinterpret_cast<const float4*>(Wa1) + tt*(528/4);
  for (int k4 = 0; k4 < 132; k4++){
    float4 w = w1[k4];
    #pragma unroll
    for (int r = 0; r < 4; r++){
      float4 xv = *reinterpret_cast<const float4*>(&X[grp*4 + r][k4*4]);
      acc[r] = fmaf(w.x, xv.x, acc[r]);
      acc[r] = fmaf(w.y, xv.y, acc[r]);
      acc[r] = fmaf(w.z, xv.z, acc[r]);
      acc[r] = fmaf(w.w, xv.w, acc[r]);
    }
  }
  float b1 = ba1[tt];
  #pragma unroll
  for (int r = 0; r < 4; r++){
    float h = acc[r] + b1;
    H1[grp*4 + r][tt] = h >= 0.f ? h : 0.2f*h;
  }
  __syncthreads();
  // stage 2: threads with tt<64 (lanes 0-63 of waves 0 and 2)
  if (tt < 64){
    float acc2[4];
    #pragma unroll
    for (int r = 0; r < 4; r++) acc2[r] = 0.f;
    const float4* w2 = reinterpret_cast<const float4*>(Wa2) + tt*(NDD/4);
    for (int k4 = 0; k4 < NDD/4; k4++){
      float4 w = w2[k4];
      #pragma unroll
      for (int r = 0; r < 4; r++){
        float4 hv = *reinterpret_cast<const float4*>(&H1[grp*4 + r][k4*4]);
        acc2[r] = fmaf(w.x, hv.x, acc2[r]);
        acc2[r] = fmaf(w.y, hv.y, acc2[r]);
        acc2[r] = fmaf(w.z, hv.z, acc2[r]);
        acc2[r] = fmaf(w.w, hv.w, acc2[r]);
      }
    }
    float b2 = ba2[tt];
    float w3 = Wa3[tt];
    float b3 = ba3[0];
    #pragma unroll
    for (int r = 0; r < 4; r++){
      float h = acc2[r] + b2;
      h = h >= 0.f ? h : 0.2f*h;
      float p = w3 * h;
      #pragma unroll
      for (int o = 32; o; o >>= 1) p += __shfl_xor(p, o, 64);
      if (tt == 0) attn[base + grp*4 + r] = p + b3;
    }
  }
}

// ---------------------------------------------------------------------------
// K9: softmax over 2048 logits; v_prior = sum_i w_i * msgs_i. One 1024-thread block.
// ---------------------------------------------------------------------------
__global__ __launch_bounds__(1024) void vprior_kernel(
    const float* __restrict__ attn, const float* __restrict__ msgsf, float* __restrict__ vp)
{
  __shared__ float A[2*NN];
  __shared__ float red[1024];
  __shared__ float Pp[8][NDD];
  int t = threadIdx.x;
  A[t] = attn[t]; A[t+1024] = attn[t+1024];
  __syncthreads();
  float mx = fmaxf(A[t], A[t+1024]);
  red[t] = mx; __syncthreads();
  for (int o = 512; o; o >>= 1){ if (t < o) red[t] = fmaxf(red[t], red[t+o]); __syncthreads(); }
  float M = red[0]; __syncthreads();
  float sm = __expf(A[t] - M) + __expf(A[t+1024] - M);
  red[t] = sm; __syncthreads();
  for (int o = 512; o; o >>= 1){ if (t < o) red[t] += red[t+o]; __syncthreads(); }
  float inv = 1.f / red[0]; __syncthreads();
  A[t]      = __expf(A[t]      - M) * inv;
  A[t+1024] = __expf(A[t+1024] - M) * inv;
  __syncthreads();
  int j = t & 127, grp = t >> 7;          // 8 groups x 128 dims
  float acc = 0.f;
  int i0 = grp * 256;
  for (int i = i0; i < i0 + 256; i++) acc = fmaf(A[i], msgsf[(size_t)i*NDD + j], acc);
  Pp[grp][j] = acc;
  __syncthreads();
  if (t < NDD){
    float v = 0.f;
    #pragma unroll
    for (int gg = 0; gg < 8; gg++) v += Pp[gg][t];
    vp[t] = v;
  }
}

// ---------------------------------------------------------------------------
// K10: integ = Wi2 @ prelu(Wi1 @ v_prior + bi1) + bi2 ; x = zt + integ ; layernorm
// ---------------------------------------------------------------------------
__global__ __launch_bounds__(256) void final_kernel(
    const float* __restrict__ vprior, const float* __restrict__ zt,
    const float* __restrict__ Wi1, const float* __restrict__ bi1, const float* __restrict__ ai,
    const float* __restrict__ Wi2, const float* __restrict__ bi2,
    const float* __restrict__ ln_g, const float* __restrict__ ln_b,
    float* __restrict__ zout)
{
  __shared__ float V[NDD];
  __shared__ float T1[NP];
  __shared__ float red[NP];
  int t = threadIdx.x;
  if (t < NDD) V[t] = vprior[t];
  __syncthreads();
  float acc = 0.f;
  const float4* w1 = reinterpret_cast<const float4*>(Wi1) + t*(NDD/4);
  for (int k4 = 0; k4 < NDD/4; k4++){
    float4 w = w1[k4];
    float4 vv = *reinterpret_cast<const float4*>(&V[k4*4]);
    acc = fmaf(w.x, vv.x, fmaf(w.y, vv.y, fmaf(w.z, vv.z, fmaf(w.w, vv.w, acc))));
  }
  float h = acc + bi1[t];
  float a = ai[0];
  T1[t] = h >= 0.f ? h : a*h;
  __syncthreads();
  float acc2 = 0.f;
  const float4* w2 = reinterpret_cast<const float4*>(Wi2) + t*(NP/4);
  for (int k4 = 0; k4 < NP/4; k4++){
    float4 w = w2[k4];
    float4 hv = *reinterpret_cast<const float4*>(&T1[k4*4]);
    acc2 = fmaf(w.x, hv.x, fmaf(w.y, hv.y, fmaf(w.z, hv.z, fmaf(w.w, hv.w, acc2))));
  }
  float x = zt[t] + acc2 + bi2[t];
  red[t] = x; __syncthreads();
  for (int o = 128; o; o >>= 1){ if (t < o) red[t] += red[t+o]; __syncthreads(); }
  float mu = red[0] * (1.f/256.f); __syncthreads();
  float d = x - mu;
  red[t] = d*d; __syncthreads();
  for (int o = 128; o; o >>= 1){ if (t < o) red[t] += red[t+o]; __syncthreads(); }
  float var = red[0] * (1.f/256.f);
  float zz = d * rsqrtf(var + 1e-5f) * ln_g[t] + ln_b[t];
  zout[t] = zz;
}

// ---------------------------------------------------------------------------
extern "C" void kernel_launch(void* const* d_in, const int* in_sizes, int n_in,
                              void* d_out, int out_size, void* d_ws, size_t ws_size,
                              hipStream_t stream)
{
  const float* tgt    = (const float*)d_in[0];
  const float* formf  = (const float*)d_in[1];
  const float* rolef  = (const float*)d_in[2];
  const int* fneigh   = (const int*)d_in[3];
  const int* fsrc     = (const int*)d_in[4];
  const int* fdst     = (const int*)d_in[5];
  const float* fy     = (const float*)d_in[6];
  const int* rneigh   = (const int*)d_in[7];
  const int* rsrc     = (const int*)d_in[8];
  const int* rdst     = (const int*)d_in[9];
  const float* ry     = (const float*)d_in[10];
  const float* drug   = (const float*)d_in[11];
  const float* Wr1 = (const float*)d_in[12];
  const float* br1 = (const float*)d_in[13];
  const float* ar1 = (const float*)d_in[14];
  const float* Wr2 = (const float*)d_in[15];
  const float* br2 = (const float*)d_in[16];
  const float* Wq  = (const float*)d_in[17];
  const float* bq  = (const float*)d_in[18];
  const float* Wk  = (const float*)d_in[19];
  const float* bk  = (const float*)d_in[20];
  const float* Wv  = (const float*)d_in[21];
  const float* bv  = (const float*)d_in[22];
  const float* lemb= (const float*)d_in[23];
  const float* Wa1 = (const float*)d_in[24];
  const float* ba1 = (const float*)d_in[25];
  const float* Wa2 = (const float*)d_in[26];
  const float* ba2 = (const float*)d_in[27];
  const float* Wa3 = (const float*)d_in[28];
  const float* ba3 = (const float*)d_in[29];
  const float* Wi1 = (const float*)d_in[30];
  const float* bi1 = (const float*)d_in[31];
  const float* ai  = (const float*)d_in[32];
  const float* Wi2 = (const float*)d_in[33];
  const float* bi2 = (const float*)d_in[34];
  const float* lng = (const float*)d_in[35];
  const float* lnb = (const float*)d_in[36];
  (void)in_sizes; (void)n_in; (void)out_size; (void)ws_size;

  float* ws = (float*)d_ws;
  // ws layout (float offsets)
  float* zt_     = ws + 0;
  float* zf_     = ws + 256;
  float* zr_     = ws + 262400;
  float* qk_     = ws + 524544;
  float* s0_     = ws + 524672;
  float* attn_   = ws + 524800;
  float* vprior_ = ws + 526848;
  float* den_    = ws + 527104;
  float* cfac_   = ws + 529152;
  float* g_      = ws + 531200;
  float* msgsf_  = ws + 793344;
  int*   count_  = (int*)(ws + 1055488);
  int*   offs_   = (int*)(ws + 1057536);
  int*   cursor_ = (int*)(ws + 1059584);
  int2*  edges_  = (int2*)(ws + 1061632);   // 2*NE int2 = 1M ints

  hipMemsetAsync(count_, 0, 2*NN*sizeof(int), stream);

  refine_kernel<<<513, 256, 0, stream>>>(tgt, formf, rolef, Wr1, br1, ar1, Wr2, br2,
                                         zt_, zf_, zr_);
  qk_kernel<<<1, 128, 0, stream>>>(zt_, Wq, bq, Wk, bk, qk_, s0_);

  hist_kernel<<<2*EB, 256, 0, stream>>>(fneigh, fsrc, rneigh, rsrc, count_);
  scan_kernel<<<2, 1024, 0, stream>>>(count_, offs_, cursor_);
  scatter_kernel<<<2*EB, 256, 0, stream>>>(fneigh, fsrc, fdst, fy,
                                           rneigh, rsrc, rdst, ry,
                                           cursor_, edges_);

  seg_kernel<<<2*NN, 256, 0, stream>>>(drug, edges_, offs_, count_, qk_, s0_,
                                       g_, den_, cfac_);

  msgs_kernel<<<2*NN/8, 128, 0, stream>>>(g_, den_, cfac_, Wv, bv,
                                          msgsf_, (float*)d_out + NP);
  attn_kernel<<<2*NN/8, 256, 0, stream>>>(zt_, zf_, zr_, lemb,
                                          Wa1, ba1, Wa2, ba2, Wa3, ba3, attn_);
  vprior_kernel<<<1, 1024, 0, stream>>>(attn_, msgsf_, vprior_);
  final_kernel<<<1, 256, 0, stream>>>(vprior_, zt_, Wi1, bi1, ai, Wi2, bi2,
                                      lng, lnb, (float*)d_out);
}

// Round 4
// 389.162 us; speedup vs baseline: 1.6973x; 1.4253x over previous
//
#include <hip/hip_runtime.h>

#define NP 256      // P
#define NDD 128     // DD
#define NN 1024     // N
#define NE 250000   // E
#define SB 62       // ceil(NE/4096) blocks per layer for hist/scatter

// ---------------------------------------------------------------------------
// K1: refine rows [target; form(1024); role(1024)] : z = W2 @ prelu(W1 @ x + b1) + b2
// 4 rows per block, 256 threads (thread = output feature), f32 out to ws.
// ---------------------------------------------------------------------------
__global__ __launch_bounds__(256) void refine_kernel(
    const float* __restrict__ tgt, const float* __restrict__ formf, const float* __restrict__ rolef,
    const float* __restrict__ Wr1, const float* __restrict__ br1, const float* __restrict__ ar1,
    const float* __restrict__ Wr2, const float* __restrict__ br2,
    float* __restrict__ zt, float* __restrict__ zf, float* __restrict__ zr)
{
  __shared__ float X[4][NP];
  __shared__ float H[4][NP];
  const int t = threadIdx.x;
  const int base = blockIdx.x * 4;
  #pragma unroll
  for (int r = 0; r < 4; r++){
    int row = base + r;
    if (row < 2*NN + 1){
      const float* xp;
      if (row == 0)        xp = tgt;
      else if (row <= NN)  xp = formf + (size_t)(row-1)*NP;
      else                 xp = rolef + (size_t)(row-NN-1)*NP;
      X[r][t] = xp[t];
    } else {
      X[r][t] = 0.f;
    }
  }
  __syncthreads();
  const float a1 = ar1[0];
  float acc[4];
  #pragma unroll
  for (int r = 0; r < 4; r++) acc[r] = 0.f;
  const float4* w1p = reinterpret_cast<const float4*>(Wr1) + t*(NP/4);
  for (int k4 = 0; k4 < NP/4; k4++){
    float4 w = w1p[k4];
    #pragma unroll
    for (int r = 0; r < 4; r++){
      float4 xv = *reinterpret_cast<const float4*>(&X[r][k4*4]);
      acc[r] = fmaf(w.x, xv.x, acc[r]);
      acc[r] = fmaf(w.y, xv.y, acc[r]);
      acc[r] = fmaf(w.z, xv.z, acc[r]);
      acc[r] = fmaf(w.w, xv.w, acc[r]);
    }
  }
  const float b1 = br1[t];
  #pragma unroll
  for (int r = 0; r < 4; r++){
    float h = acc[r] + b1;
    H[r][t] = h >= 0.f ? h : a1*h;
  }
  __syncthreads();
  #pragma unroll
  for (int r = 0; r < 4; r++) acc[r] = 0.f;
  const float4* w2p = reinterpret_cast<const float4*>(Wr2) + t*(NP/4);
  for (int k4 = 0; k4 < NP/4; k4++){
    float4 w = w2p[k4];
    #pragma unroll
    for (int r = 0; r < 4; r++){
      float4 hv = *reinterpret_cast<const float4*>(&H[r][k4*4]);
      acc[r] = fmaf(w.x, hv.x, acc[r]);
      acc[r] = fmaf(w.y, hv.y, acc[r]);
      acc[r] = fmaf(w.z, hv.z, acc[r]);
      acc[r] = fmaf(w.w, hv.w, acc[r]);
    }
  }
  const float b2 = br2[t];
  #pragma unroll
  for (int r = 0; r < 4; r++){
    int row = base + r;
    if (row < 2*NN + 1){
      float v = acc[r] + b2;
      float* op;
      if (row == 0)        op = zt;
      else if (row <= NN)  op = zf + (size_t)(row-1)*NP;
      else                 op = zr + (size_t)(row-NN-1)*NP;
      op[t] = v;
    }
  }
}

// ---------------------------------------------------------------------------
// K2: Qv = Wq@zt + bq ; qk = (Wk^T @ Qv)/sqrt(DD) ; s0 = (bk . Qv)/sqrt(DD)
// ---------------------------------------------------------------------------
__global__ __launch_bounds__(128) void qk_kernel(
    const float* __restrict__ zt,
    const float* __restrict__ Wq, const float* __restrict__ bq,
    const float* __restrict__ Wk, const float* __restrict__ bk,
    float* __restrict__ qk, float* __restrict__ s0)
{
  __shared__ float Z[NP];
  __shared__ float Q[NDD];
  __shared__ float red[NDD];
  int t = threadIdx.x;
  Z[t] = zt[t]; Z[t+128] = zt[t+128];
  __syncthreads();
  float acc = 0.f;
  const float4* wq = reinterpret_cast<const float4*>(Wq) + t*(NP/4);
  for (int k4 = 0; k4 < NP/4; k4++){
    float4 w = wq[k4];
    float4 zv = *reinterpret_cast<const float4*>(&Z[k4*4]);
    acc = fmaf(w.x, zv.x, fmaf(w.y, zv.y, fmaf(w.z, zv.z, fmaf(w.w, zv.w, acc))));
  }
  float qv = acc + bq[t];
  Q[t] = qv;
  __syncthreads();
  float a2 = 0.f;
  for (int j = 0; j < NDD; j++) a2 = fmaf(Wk[j*NDD + t], Q[j], a2);
  const float rs = 0.08838834764831845f;  // 1/sqrt(128)
  qk[t] = a2 * rs;
  red[t] = bk[t] * qv;
  __syncthreads();
  for (int o = 64; o; o >>= 1){ if (t < o) red[t] += red[t+o]; __syncthreads(); }
  if (t == 0) s0[0] = red[0] * rs;
}

// ---------------------------------------------------------------------------
// Segment id: fast path (sorted int neighbors with neigh[s]==s => pos=s),
// fallback to binary search.
// ---------------------------------------------------------------------------
__device__ __forceinline__ int seg_of(const int* NB, int s){
  if ((unsigned)s < NN && NB[s] == s) return s;
  int lo = 0, hi = NN;
  while (lo < hi){ int mid = (lo+hi)>>1; if (NB[mid] < s) lo = mid+1; else hi = mid; }
  return lo < NN ? lo : NN-1;
}

// ---------------------------------------------------------------------------
// K3: histogram by segment, two-level: LDS histogram per block (4096 edges),
// then one global atomicAdd per nonzero bin. Both layers in one launch.
// ---------------------------------------------------------------------------
__global__ __launch_bounds__(1024) void hist_kernel(
    const int* __restrict__ neighF, const int* __restrict__ srcF,
    const int* __restrict__ neighR, const int* __restrict__ srcR,
    int* __restrict__ count)
{
  __shared__ int NB[NN];
  __shared__ int lh[NN];
  int bi = blockIdx.x;
  int role = bi >= SB ? 1 : 0;
  int blk = bi - role*SB;
  const int* neigh = role ? neighR : neighF;
  const int* src   = role ? srcR   : srcF;
  int* cnt = count + role*NN;
  int t = threadIdx.x;
  NB[t] = neigh[t];
  lh[t] = 0;
  __syncthreads();
  #pragma unroll
  for (int i = 0; i < 4; i++){
    int e = blk*4096 + i*1024 + t;
    if (e < NE){
      int s = src[e];
      int pos = seg_of(NB, s);
      if (NB[pos] == s) atomicAdd(&lh[pos], 1);
    }
  }
  __syncthreads();
  int c = lh[t];
  if (c > 0) atomicAdd(&cnt[t], c);
}

__global__ __launch_bounds__(1024) void scan_kernel(
    const int* __restrict__ count, int* __restrict__ offsets, int* __restrict__ cursor)
{
  __shared__ int s[NN];
  int l = blockIdx.x;
  int t = threadIdx.x;
  int c = count[l*NN + t];
  s[t] = c; __syncthreads();
  for (int o = 1; o < NN; o <<= 1){
    int v = (t >= o) ? s[t-o] : 0;
    __syncthreads();
    s[t] += v;
    __syncthreads();
  }
  int ex = s[t] - c;
  offsets[l*NN + t] = ex;
  cursor[l*NN + t]  = ex;
}

// ---------------------------------------------------------------------------
// K4: scatter edges into segment-sorted order (non-stable; order within a
// segment is irrelevant to the math). Two-level: LDS local counts, one global
// atomicAdd per nonzero bin reserves a contiguous range, edges write at
// base + localIdx => per-block per-segment writes are contiguous.
// ---------------------------------------------------------------------------
__global__ __launch_bounds__(1024) void scatter_kernel(
    const int* __restrict__ neighF, const int* __restrict__ srcF,
    const int* __restrict__ dstF, const float* __restrict__ yF,
    const int* __restrict__ neighR, const int* __restrict__ srcR,
    const int* __restrict__ dstR, const float* __restrict__ yR,
    int* __restrict__ cursor, int2* __restrict__ edges)
{
  __shared__ int NB[NN];
  __shared__ int lcur[NN];
  __shared__ int lbase[NN];
  int bi = blockIdx.x;
  int role = bi >= SB ? 1 : 0;
  int blk = bi - role*SB;
  const int* neigh = role ? neighR : neighF;
  const int* src   = role ? srcR   : srcF;
  const int* dst   = role ? dstR   : dstF;
  const float* yb  = role ? yR     : yF;
  int* cur  = cursor + role*NN;
  int2* ed  = edges  + (size_t)role*NE;
  int t = threadIdx.x;
  NB[t] = neigh[t];
  lcur[t] = 0;
  __syncthreads();
  int segr[4], locr[4]; int2 edr[4];
  #pragma unroll
  for (int i = 0; i < 4; i++){
    int e = blk*4096 + i*1024 + t;
    segr[i] = -1;
    if (e < NE){
      int s = src[e];
      int pos = seg_of(NB, s);
      if (NB[pos] == s){
        segr[i] = pos;
        edr[i]  = make_int2(dst[e], __float_as_int(yb[e]));
        locr[i] = atomicAdd(&lcur[pos], 1);
      }
    }
  }
  __syncthreads();
  int c = lcur[t];
  if (c > 0) lbase[t] = atomicAdd(&cur[t], c);
  __syncthreads();
  #pragma unroll
  for (int i = 0; i < 4; i++){
    if (segr[i] >= 0){
      ed[(size_t)(lbase[segr[i]] + locr[i])] = edr[i];
    }
  }
}

// ---------------------------------------------------------------------------
// K6: per-(layer,segment) softmax-weighted accumulation.
// 4 waves/block; each 32-lane half-wave handles one edge with float4 lanes
// (32 lanes x 4 dims = 128). 4 pairs (8 edges) batched per iteration for MLP.
// No max-subtraction: logits are O(1e-2), exp safe; num/den invariant.
// ---------------------------------------------------------------------------
__global__ __launch_bounds__(256) void seg_kernel(
    const float* __restrict__ drug,
    const int2* __restrict__ edges,
    const int* __restrict__ offsets, const int* __restrict__ count,
    const float* __restrict__ qk, const float* __restrict__ s0p,
    float* __restrict__ g, float* __restrict__ den, float* __restrict__ cfac)
{
  int b = blockIdx.x;                 // l*1024 + n
  int tid = threadIdx.x;
  int w = tid >> 6, lane = tid & 63, l32 = lane & 31, half = lane >> 5;
  int off = offsets[b], cnt = count[b];
  int l = b >> 10;
  const int2* eb = edges + (size_t)l*NE;
  float4 q = reinterpret_cast<const float4*>(qk)[l32];
  float s0 = s0p[0];
  int chunk = (cnt + 3) >> 2;
  int start = w*chunk;
  int end = min(start + chunk, cnt);
  float dn = 0.f, cc = 0.f;
  float4 ga = make_float4(0.f,0.f,0.f,0.f);
  for (int i = start; i < end; i += 8){
    int dstp[4]; float yp[4]; bool vp[4];
    #pragma unroll
    for (int p2 = 0; p2 < 4; p2++){
      int idx = i + 2*p2 + half;
      bool v = idx < end;
      int2 e = eb[off + (v ? idx : start)];
      dstp[p2] = e.x; yp[p2] = __int_as_float(e.y); vp[p2] = v;
    }
    float4 dv[4];
    #pragma unroll
    for (int p2 = 0; p2 < 4; p2++){
      dv[p2] = reinterpret_cast<const float4*>(drug + (size_t)dstp[p2]*NDD)[l32];
    }
    #pragma unroll
    for (int p2 = 0; p2 < 4; p2++){
      float4 d = dv[p2];
      float s = fmaf(d.x, q.x, fmaf(d.y, q.y, fmaf(d.z, q.z, d.w*q.w)));
      s += __shfl_xor(s, 16, 64);
      s += __shfl_xor(s,  8, 64);
      s += __shfl_xor(s,  4, 64);
      s += __shfl_xor(s,  2, 64);
      s += __shfl_xor(s,  1, 64);
      float ex = vp[p2] ? __expf(s + s0) : 0.f;
      float wv = ex * (yp[p2] - 6.0f);
      dn += ex; cc += wv;
      ga.x = fmaf(wv, d.x, ga.x);
      ga.y = fmaf(wv, d.y, ga.y);
      ga.z = fmaf(wv, d.z, ga.z);
      ga.w = fmaf(wv, d.w, ga.w);
    }
  }
  __shared__ float4 sG[8][32];
  __shared__ float sD[8], sC[8];
  int slot = w*2 + half;
  sG[slot][l32] = ga;
  if (l32 == 0){ sD[slot] = dn; sC[slot] = cc; }
  __syncthreads();
  if (tid < NDD){
    int a = tid >> 2, c = tid & 3;
    float v = 0.f;
    #pragma unroll
    for (int k = 0; k < 8; k++)
      v += reinterpret_cast<const float*>(&sG[k][a])[c];
    g[(size_t)b*NDD + tid] = v;
    if (tid == 0){
      float ds = 0.f, cs = 0.f;
      #pragma unroll
      for (int k = 0; k < 8; k++){ ds += sD[k]; cs += sC[k]; }
      den[b] = ds; cfac[b] = cs;
    }
  }
}

// ---------------------------------------------------------------------------
// K7: msgs[row] = (Wv @ g[row] + bv*c[row]) / den[row]  (0 if den<=0)
// ---------------------------------------------------------------------------
__global__ __launch_bounds__(128) void msgs_kernel(
    const float* __restrict__ g, const float* __restrict__ den, const float* __restrict__ cfac,
    const float* __restrict__ Wv, const float* __restrict__ bv,
    float* __restrict__ msgsf, float* __restrict__ outm)
{
  __shared__ float G[8][NDD];
  int t = threadIdx.x;
  int base = blockIdx.x*8;
  #pragma unroll
  for (int r = 0; r < 8; r++) G[r][t] = g[(size_t)(base+r)*NDD + t];
  __syncthreads();
  float acc[8];
  #pragma unroll
  for (int r = 0; r < 8; r++) acc[r] = 0.f;
  const float4* wv4 = reinterpret_cast<const float4*>(Wv) + t*(NDD/4);
  for (int k4 = 0; k4 < NDD/4; k4++){
    float4 w = wv4[k4];
    #pragma unroll
    for (int r = 0; r < 8; r++){
      float4 gv = *reinterpret_cast<const float4*>(&G[r][k4*4]);
      acc[r] = fmaf(w.x, gv.x, acc[r]);
      acc[r] = fmaf(w.y, gv.y, acc[r]);
      acc[r] = fmaf(w.z, gv.z, acc[r]);
      acc[r] = fmaf(w.w, gv.w, acc[r]);
    }
  }
  float bvj = bv[t];
  #pragma unroll
  for (int r = 0; r < 8; r++){
    int row = base + r;
    float dn = den[row];
    float v = 0.f;
    if (dn > 0.f) v = (acc[r] + bvj*cfac[row]) / fmaxf(dn, 1e-30f);
    msgsf[(size_t)row*NDD + t] = v;
    outm [(size_t)row*NDD + t] = v;
  }
}

// ---------------------------------------------------------------------------
// K8: attention logits. 8 rows/block, 256 threads (2 groups x 128).
// ---------------------------------------------------------------------------
__global__ __launch_bounds__(256) void attn_kernel(
    const float* __restrict__ zt, const float* __restrict__ zf, const float* __restrict__ zr,
    const float* __restrict__ lemb,
    const float* __restrict__ Wa1, const float* __restrict__ ba1,
    const float* __restrict__ Wa2, const float* __restrict__ ba2,
    const float* __restrict__ Wa3, const float* __restrict__ ba3,
    float* __restrict__ attn)
{
  __shared__ float X[8][528];
  __shared__ float H1[8][NDD];
  int t = threadIdx.x;
  int tt = t & 127, grp = t >> 7;
  int base = blockIdx.x*8;
  for (int r = 0; r < 8; r++){
    int i = base + r;
    int layer = i >> 10, nn = i & (NN-1);
    const float* zn = (layer == 0) ? (zf + (size_t)nn*NP) : (zr + (size_t)nn*NP);
    for (int idx = t; idx < 528; idx += 256){
      float v;
      if (idx < NP)        v = zt[idx];
      else if (idx < 2*NP) v = zn[idx - NP];
      else                 v = lemb[layer*16 + (idx - 2*NP)];
      X[r][idx] = v;
    }
  }
  __syncthreads();
  float acc[4];
  #pragma unroll
  for (int r = 0; r < 4; r++) acc[r] = 0.f;
  const float4* w1 = reinterpret_cast<const float4*>(Wa1) + tt*(528/4);
  for (int k4 = 0; k4 < 132; k4++){
    float4 w = w1[k4];
    #pragma unroll
    for (int r = 0; r < 4; r++){
      float4 xv = *reinterpret_cast<const float4*>(&X[grp*4 + r][k4*4]);
      acc[r] = fmaf(w.x, xv.x, acc[r]);
      acc[r] = fmaf(w.y, xv.y, acc[r]);
      acc[r] = fmaf(w.z, xv.z, acc[r]);
      acc[r] = fmaf(w.w, xv.w, acc[r]);
    }
  }
  float b1 = ba1[tt];
  #pragma unroll
  for (int r = 0; r < 4; r++){
    float h = acc[r] + b1;
    H1[grp*4 + r][tt] = h >= 0.f ? h : 0.2f*h;
  }
  __syncthreads();
  if (tt < 64){
    float acc2[4];
    #pragma unroll
    for (int r = 0; r < 4; r++) acc2[r] = 0.f;
    const float4* w2 = reinterpret_cast<const float4*>(Wa2) + tt*(NDD/4);
    for (int k4 = 0; k4 < NDD/4; k4++){
      float4 w = w2[k4];
      #pragma unroll
      for (int r = 0; r < 4; r++){
        float4 hv = *reinterpret_cast<const float4*>(&H1[grp*4 + r][k4*4]);
        acc2[r] = fmaf(w.x, hv.x, acc2[r]);
        acc2[r] = fmaf(w.y, hv.y, acc2[r]);
        acc2[r] = fmaf(w.z, hv.z, acc2[r]);
        acc2[r] = fmaf(w.w, hv.w, acc2[r]);
      }
    }
    float b2 = ba2[tt];
    float w3 = Wa3[tt];
    float b3 = ba3[0];
    #pragma unroll
    for (int r = 0; r < 4; r++){
      float h = acc2[r] + b2;
      h = h >= 0.f ? h : 0.2f*h;
      float p = w3 * h;
      #pragma unroll
      for (int o = 32; o; o >>= 1) p += __shfl_xor(p, o, 64);
      if (tt == 0) attn[base + grp*4 + r] = p + b3;
    }
  }
}

// ---------------------------------------------------------------------------
// K9: softmax over 2048 logits; v_prior = sum_i w_i * msgs_i. One 1024-thread block.
// ---------------------------------------------------------------------------
__global__ __launch_bounds__(1024) void vprior_kernel(
    const float* __restrict__ attn, const float* __restrict__ msgsf, float* __restrict__ vp)
{
  __shared__ float A[2*NN];
  __shared__ float red[1024];
  __shared__ float Pp[8][NDD];
  int t = threadIdx.x;
  A[t] = attn[t]; A[t+1024] = attn[t+1024];
  __syncthreads();
  float mx = fmaxf(A[t], A[t+1024]);
  red[t] = mx; __syncthreads();
  for (int o = 512; o; o >>= 1){ if (t < o) red[t] = fmaxf(red[t], red[t+o]); __syncthreads(); }
  float M = red[0]; __syncthreads();
  float sm = __expf(A[t] - M) + __expf(A[t+1024] - M);
  red[t] = sm; __syncthreads();
  for (int o = 512; o; o >>= 1){ if (t < o) red[t] += red[t+o]; __syncthreads(); }
  float inv = 1.f / red[0]; __syncthreads();
  A[t]      = __expf(A[t]      - M) * inv;
  A[t+1024] = __expf(A[t+1024] - M) * inv;
  __syncthreads();
  int j = t & 127, grp = t >> 7;          // 8 groups x 128 dims
  float acc = 0.f;
  int i0 = grp * 256;
  for (int i = i0; i < i0 + 256; i++) acc = fmaf(A[i], msgsf[(size_t)i*NDD + j], acc);
  Pp[grp][j] = acc;
  __syncthreads();
  if (t < NDD){
    float v = 0.f;
    #pragma unroll
    for (int gg = 0; gg < 8; gg++) v += Pp[gg][t];
    vp[t] = v;
  }
}

// ---------------------------------------------------------------------------
// K10: integ = Wi2 @ prelu(Wi1 @ v_prior + bi1) + bi2 ; x = zt + integ ; layernorm
// ---------------------------------------------------------------------------
__global__ __launch_bounds__(256) void final_kernel(
    const float* __restrict__ vprior, const float* __restrict__ zt,
    const float* __restrict__ Wi1, const float* __restrict__ bi1, const float* __restrict__ ai,
    const float* __restrict__ Wi2, const float* __restrict__ bi2,
    const float* __restrict__ ln_g, const float* __restrict__ ln_b,
    float* __restrict__ zout)
{
  __shared__ float V[NDD];
  __shared__ float T1[NP];
  __shared__ float red[NP];
  int t = threadIdx.x;
  if (t < NDD) V[t] = vprior[t];
  __syncthreads();
  float acc = 0.f;
  const float4* w1 = reinterpret_cast<const float4*>(Wi1) + t*(NDD/4);
  for (int k4 = 0; k4 < NDD/4; k4++){
    float4 w = w1[k4];
    float4 vv = *reinterpret_cast<const float4*>(&V[k4*4]);
    acc = fmaf(w.x, vv.x, fmaf(w.y, vv.y, fmaf(w.z, vv.z, fmaf(w.w, vv.w, acc))));
  }
  float h = acc + bi1[t];
  float a = ai[0];
  T1[t] = h >= 0.f ? h : a*h;
  __syncthreads();
  float acc2 = 0.f;
  const float4* w2 = reinterpret_cast<const float4*>(Wi2) + t*(NP/4);
  for (int k4 = 0; k4 < NP/4; k4++){
    float4 w = w2[k4];
    float4 hv = *reinterpret_cast<const float4*>(&T1[k4*4]);
    acc2 = fmaf(w.x, hv.x, fmaf(w.y, hv.y, fmaf(w.z, hv.z, fmaf(w.w, hv.w, acc2))));
  }
  float x = zt[t] + acc2 + bi2[t];
  red[t] = x; __syncthreads();
  for (int o = 128; o; o >>= 1){ if (t < o) red[t] += red[t+o]; __syncthreads(); }
  float mu = red[0] * (1.f/256.f); __syncthreads();
  float d = x - mu;
  red[t] = d*d; __syncthreads();
  for (int o = 128; o; o >>= 1){ if (t < o) red[t] += red[t+o]; __syncthreads(); }
  float var = red[0] * (1.f/256.f);
  float zz = d * rsqrtf(var + 1e-5f) * ln_g[t] + ln_b[t];
  zout[t] = zz;
}

// ---------------------------------------------------------------------------
extern "C" void kernel_launch(void* const* d_in, const int* in_sizes, int n_in,
                              void* d_out, int out_size, void* d_ws, size_t ws_size,
                              hipStream_t stream)
{
  const float* tgt    = (const float*)d_in[0];
  const float* formf  = (const float*)d_in[1];
  const float* rolef  = (const float*)d_in[2];
  const int* fneigh   = (const int*)d_in[3];
  const int* fsrc     = (const int*)d_in[4];
  const int* fdst     = (const int*)d_in[5];
  const float* fy     = (const float*)d_in[6];
  const int* rneigh   = (const int*)d_in[7];
  const int* rsrc     = (const int*)d_in[8];
  const int* rdst     = (const int*)d_in[9];
  const float* ry     = (const float*)d_in[10];
  const float* drug   = (const float*)d_in[11];
  const float* Wr1 = (const float*)d_in[12];
  const float* br1 = (const float*)d_in[13];
  const float* ar1 = (const float*)d_in[14];
  const float* Wr2 = (const float*)d_in[15];
  const float* br2 = (const float*)d_in[16];
  const float* Wq  = (const float*)d_in[17];
  const float* bq  = (const float*)d_in[18];
  const float* Wk  = (const float*)d_in[19];
  const float* bk  = (const float*)d_in[20];
  const float* Wv  = (const float*)d_in[21];
  const float* bv  = (const float*)d_in[22];
  const float* lemb= (const float*)d_in[23];
  const float* Wa1 = (const float*)d_in[24];
  const float* ba1 = (const float*)d_in[25];
  const float* Wa2 = (const float*)d_in[26];
  const float* ba2 = (const float*)d_in[27];
  const float* Wa3 = (const float*)d_in[28];
  const float* ba3 = (const float*)d_in[29];
  const float* Wi1 = (const float*)d_in[30];
  const float* bi1 = (const float*)d_in[31];
  const float* ai  = (const float*)d_in[32];
  const float* Wi2 = (const float*)d_in[33];
  const float* bi2 = (const float*)d_in[34];
  const float* lng = (const float*)d_in[35];
  const float* lnb = (const float*)d_in[36];
  (void)in_sizes; (void)n_in; (void)out_size; (void)ws_size;

  float* ws = (float*)d_ws;
  // ws layout (float offsets)
  float* zt_     = ws + 0;
  float* zf_     = ws + 256;
  float* zr_     = ws + 262400;
  float* qk_     = ws + 524544;
  float* s0_     = ws + 524672;
  float* attn_   = ws + 524800;
  float* vprior_ = ws + 526848;
  float* den_    = ws + 527104;
  float* cfac_   = ws + 529152;
  float* g_      = ws + 531200;
  float* msgsf_  = ws + 793344;
  int*   count_  = (int*)(ws + 1055488);
  int*   offs_   = (int*)(ws + 1057536);
  int*   cursor_ = (int*)(ws + 1059584);
  int2*  edges_  = (int2*)(ws + 1061632);   // 2*NE int2 = 1M ints

  hipMemsetAsync(count_, 0, 2*NN*sizeof(int), stream);

  refine_kernel<<<513, 256, 0, stream>>>(tgt, formf, rolef, Wr1, br1, ar1, Wr2, br2,
                                         zt_, zf_, zr_);
  qk_kernel<<<1, 128, 0, stream>>>(zt_, Wq, bq, Wk, bk, qk_, s0_);

  hist_kernel<<<2*SB, 1024, 0, stream>>>(fneigh, fsrc, rneigh, rsrc, count_);
  scan_kernel<<<2, 1024, 0, stream>>>(count_, offs_, cursor_);
  scatter_kernel<<<2*SB, 1024, 0, stream>>>(fneigh, fsrc, fdst, fy,
                                            rneigh, rsrc, rdst, ry,
                                            cursor_, edges_);

  seg_kernel<<<2*NN, 256, 0, stream>>>(drug, edges_, offs_, count_, qk_, s0_,
                                       g_, den_, cfac_);

  msgs_kernel<<<2*NN/8, 128, 0, stream>>>(g_, den_, cfac_, Wv, bv,
                                          msgsf_, (float*)d_out + NP);
  attn_kernel<<<2*NN/8, 256, 0, stream>>>(zt_, zf_, zr_, lemb,
                                          Wa1, ba1, Wa2, ba2, Wa3, ba3, attn_);
  vprior_kernel<<<1, 1024, 0, stream>>>(attn_, msgsf_, vprior_);
  final_kernel<<<1, 256, 0, stream>>>(vprior_, zt_, Wi1, bi1, ai, Wi2, bi2,
                                      lng, lnb, (float*)d_out);
}